// Round 1
// baseline (2538.128 us; speedup 1.0000x reference)
//
#include <hip/hip_runtime.h>
#include <math.h>

#define D_MODEL 768
#define D_STATE 16
#define NGRID   3
#define BB      2
#define LL      2048
#define MM      (BB * LL)   // 4096

// ---------------------------------------------------------------------------
// Generic fp32 tiled GEMM: C[M,N] = Atransform(A)[M,K] @ B[K,N] (+ bias)
// MODE 0: plain A
// MODE 1: augmented KAN features from x_norm:  f<768 -> silu(xn[i,f])
//         f>=768 -> kk=f-768, d=kk/3, g=kk%3, phi = exp(-(xn[i,d]-(g-1))^2)
// MODE 2: A = y_core[i,f] * silu(z[i,f]) with z = xz[i, 768+f]
// BM=BN=64, BK=16, 256 threads, 4x4 per thread.
// M, K assumed multiples of 64/16; N bounds-checked.
// ---------------------------------------------------------------------------
template<int MODE>
__global__ void gemm_kernel(const float* __restrict__ A,
                            const float* __restrict__ A2,
                            const float* __restrict__ Bm,
                            const float* __restrict__ bias,
                            float* __restrict__ C,
                            int M, int N, int K, int lda, int ldb, int ldc)
{
    const int BM = 64, BN = 64, BK = 16;
    __shared__ float As[BM][BK + 1];   // +1 pad: conflict-free stores/reads
    __shared__ float Bs[BK][BN];

    int tid = threadIdx.x;             // 0..255
    int tx = tid & 15;                 // 0..15
    int ty = tid >> 4;                 // 0..15
    int row0 = blockIdx.y * BM;
    int col0 = blockIdx.x * BN;

    float acc[4][4] = {};

    for (int k0 = 0; k0 < K; k0 += BK) {
        // ---- load A tile (64 x 16) : 4 elements / thread ----
        #pragma unroll
        for (int e = 0; e < 4; ++e) {
            int flat = tid + e * 256;          // 0..1023
            int kl = flat & 15;
            int ml = flat >> 4;
            int i = row0 + ml;
            int f = k0 + kl;
            float v;
            if (MODE == 0) {
                v = A[(size_t)i * lda + f];
            } else if (MODE == 1) {
                if (f < D_MODEL) {
                    float xv = A[(size_t)i * D_MODEL + f];
                    v = xv / (1.0f + __expf(-xv));          // silu
                } else {
                    int kk = f - D_MODEL;
                    int d  = kk / 3;
                    int g  = kk - d * 3;
                    float xv = A[(size_t)i * D_MODEL + d];
                    float t  = xv - (float)(g - 1);          // grid {-1,0,1}
                    v = __expf(-t * t);                      // RBF
                }
            } else { // MODE 2
                float yv = A[(size_t)i * D_MODEL + f];
                float zv = A2[(size_t)i * (2 * D_MODEL) + D_MODEL + f];
                v = yv * (zv / (1.0f + __expf(-zv)));
            }
            As[ml][kl] = v;
        }
        // ---- load B tile (16 x 64) : 4 elements / thread ----
        #pragma unroll
        for (int e = 0; e < 4; ++e) {
            int flat = tid + e * 256;
            int nl = flat & 63;
            int kl = flat >> 6;
            int col = col0 + nl;
            Bs[kl][nl] = (col < N) ? Bm[(size_t)(k0 + kl) * ldb + col] : 0.0f;
        }
        __syncthreads();

        #pragma unroll
        for (int k = 0; k < BK; ++k) {
            float a[4], b[4];
            #pragma unroll
            for (int i2 = 0; i2 < 4; ++i2) a[i2] = As[ty * 4 + i2][k];
            #pragma unroll
            for (int j = 0; j < 4; ++j)    b[j] = Bs[k][tx * 4 + j];
            #pragma unroll
            for (int i2 = 0; i2 < 4; ++i2)
                #pragma unroll
                for (int j = 0; j < 4; ++j)
                    acc[i2][j] += a[i2] * b[j];
        }
        __syncthreads();
    }

    #pragma unroll
    for (int i2 = 0; i2 < 4; ++i2) {
        int row = row0 + ty * 4 + i2;
        #pragma unroll
        for (int j = 0; j < 4; ++j) {
            int col = col0 + tx * 4 + j;
            if (col < N) {
                float bv = bias ? bias[col] : 0.0f;
                C[(size_t)row * ldc + col] = acc[i2][j] + bv;
            }
        }
    }
}

// ---------------------------------------------------------------------------
// LayerNorm over x_proj = xz[:, 0:768] -> x_norm [M, 768]
// one block (256 threads) per row
// ---------------------------------------------------------------------------
__global__ void ln_kernel(const float* __restrict__ xz,
                          const float* __restrict__ gamma,
                          const float* __restrict__ beta,
                          float* __restrict__ xn)
{
    int row = blockIdx.x;
    const float* xp = xz + (size_t)row * (2 * D_MODEL);
    int tid  = threadIdx.x;
    int lane = tid & 63, wave = tid >> 6;

    float v[3];
    float s = 0.f, s2 = 0.f;
    #pragma unroll
    for (int e = 0; e < 3; ++e) {
        v[e] = xp[tid + e * 256];
        s  += v[e];
        s2 += v[e] * v[e];
    }
    #pragma unroll
    for (int off = 32; off >= 1; off >>= 1) {
        s  += __shfl_xor(s,  off);
        s2 += __shfl_xor(s2, off);
    }
    __shared__ float red[2][4];
    if (lane == 0) { red[0][wave] = s; red[1][wave] = s2; }
    __syncthreads();
    s  = red[0][0] + red[0][1] + red[0][2] + red[0][3];
    s2 = red[1][0] + red[1][1] + red[1][2] + red[1][3];

    const float inv = 1.0f / (float)D_MODEL;
    float mean = s * inv;
    float var  = s2 * inv - mean * mean;
    float rstd = rsqrtf(var + 1e-5f);

    #pragma unroll
    for (int e = 0; e < 3; ++e) {
        int c = tid + e * 256;
        xn[(size_t)row * D_MODEL + c] = (v[e] - mean) * rstd * gamma[c] + beta[c];
    }
}

// ---------------------------------------------------------------------------
// Repack the six KAN weight arrays into W_cat [3072, 800]
// rows: 0..767 base (d), 768..3071 spline (d*3+g)
// cols: 0..767 delta, 768..783 B, 784..799 C
// ---------------------------------------------------------------------------
__global__ void repack_kernel(const float* __restrict__ kd_b, const float* __restrict__ kd_s,
                              const float* __restrict__ kb_b, const float* __restrict__ kb_s,
                              const float* __restrict__ kc_b, const float* __restrict__ kc_s,
                              float* __restrict__ Wcat)
{
    int idx = blockIdx.x * 256 + threadIdx.x;
    if (idx >= 3072 * 800) return;
    int f = idx / 800;
    int o = idx - f * 800;
    float v;
    if (f < D_MODEL) {
        if (o < 768)      v = kd_b[(size_t)f * 768 + o];
        else if (o < 784) v = kb_b[(size_t)f * 16 + (o - 768)];
        else              v = kc_b[(size_t)f * 16 + (o - 784)];
    } else {
        int sidx = f - D_MODEL;                 // d*3+g
        if (o < 768)      v = kd_s[(size_t)sidx * 768 + o];
        else if (o < 784) v = kb_s[(size_t)sidx * 16 + (o - 768)];
        else              v = kc_s[(size_t)sidx * 16 + (o - 784)];
    }
    Wcat[idx] = v;
}

// ---------------------------------------------------------------------------
// Selective scan.  S [M, 800] = [pre_delta(768) | B(16) | C(16)]
// block: 256 threads = 4 waves; lane = dsub*16 + n ; wave covers 4 d, block 16 d
// grid: B * (768/16) = 96 blocks
// y_core[row,d] = sum_n C[row,n] * h[row,d,n] + D[d] * x_proj[row,d]
// ---------------------------------------------------------------------------
__global__ void scan_kernel(const float* __restrict__ S,
                            const float* __restrict__ xz,
                            const float* __restrict__ prio,
                            const float* __restrict__ A_log,
                            const float* __restrict__ Dp,
                            float* __restrict__ y_core)
{
    int blk  = blockIdx.x;
    int b    = blk / (D_MODEL / 16);
    int dblk = blk % (D_MODEL / 16);
    int tid  = threadIdx.x;
    int wave = tid >> 6, lane = tid & 63;
    int dsub = lane >> 4, n = lane & 15;
    int d = dblk * 16 + wave * 4 + dsub;

    float Acont = -expf(A_log[(size_t)d * D_STATE + n]);
    float Dv = Dp[d];
    float h = 0.0f;

    for (int l = 0; l < LL; ++l) {
        int row = b * LL + l;
        const float* sr = S + (size_t)row * 800;
        float dpre = sr[d];                    // broadcast among 16 lanes
        float Bn   = sr[D_MODEL + n];
        float Cn   = sr[D_MODEL + 16 + n];
        float xp   = xz[(size_t)row * (2 * D_MODEL) + d];
        float pr   = prio[row];

        float sp    = (dpre > 20.0f) ? dpre : log1pf(expf(dpre));   // softplus
        float delta = sp * expf(-pr);
        float dA    = expf(delta * Acont);
        h = dA * h + delta * Bn * xp;

        float acc = Cn * h;
        acc += __shfl_xor(acc, 1);
        acc += __shfl_xor(acc, 2);
        acc += __shfl_xor(acc, 4);
        acc += __shfl_xor(acc, 8);
        if (n == 0)
            y_core[(size_t)row * D_MODEL + d] = acc + Dv * xp;
    }
}

// ---------------------------------------------------------------------------
extern "C" void kernel_launch(void* const* d_in, const int* in_sizes, int n_in,
                              void* d_out, int out_size, void* d_ws, size_t ws_size,
                              hipStream_t stream)
{
    const float* x        = (const float*)d_in[0];
    const float* prio     = (const float*)d_in[1];
    const float* W_in     = (const float*)d_in[2];
    const float* b_in     = (const float*)d_in[3];
    const float* ln_g     = (const float*)d_in[4];
    const float* ln_b     = (const float*)d_in[5];
    const float* kd_base  = (const float*)d_in[6];
    const float* kd_spl   = (const float*)d_in[7];
    const float* kb_base  = (const float*)d_in[8];
    const float* kb_spl   = (const float*)d_in[9];
    const float* kc_base  = (const float*)d_in[10];
    const float* kc_spl   = (const float*)d_in[11];
    const float* A_log    = (const float*)d_in[12];
    const float* D_param  = (const float*)d_in[13];
    const float* W_out    = (const float*)d_in[14];
    const float* b_out    = (const float*)d_in[15];
    float* out = (float*)d_out;

    float* ws   = (float*)d_ws;
    float* xz   = ws;                                   // 4096*1536
    float* xn   = xz + (size_t)MM * 1536;               // 4096*768
    float* Wcat = xn + (size_t)MM * 768;                // 3072*800
    float* S    = Wcat + (size_t)3072 * 800;            // 4096*800
    float* yc   = S + (size_t)MM * 800;                 // 4096*768

    // 1) xz = x @ W_in + b_in          [4096,1536]
    gemm_kernel<0><<<dim3(1536 / 64, MM / 64), 256, 0, stream>>>(
        x, nullptr, W_in, b_in, xz, MM, 1536, D_MODEL, D_MODEL, 1536, 1536);

    // 2) x_norm = LN(x_proj)           [4096,768]
    ln_kernel<<<MM, 256, 0, stream>>>(xz, ln_g, ln_b, xn);

    // 3) W_cat repack                  [3072,800]
    repack_kernel<<<(3072 * 800 + 255) / 256, 256, 0, stream>>>(
        kd_base, kd_spl, kb_base, kb_spl, kc_base, kc_spl, Wcat);

    // 4) S = Aug(x_norm) @ W_cat       [4096,800]
    gemm_kernel<1><<<dim3((800 + 63) / 64, MM / 64), 256, 0, stream>>>(
        xn, nullptr, Wcat, nullptr, S, MM, 800, 3072, D_MODEL, 800, 800);

    // 5) selective scan -> y_core      [4096,768]
    scan_kernel<<<BB * (D_MODEL / 16), 256, 0, stream>>>(
        S, xz, prio, A_log, D_param, yc);

    // 6) out = (y_core * silu(z)) @ W_out + b_out
    gemm_kernel<2><<<dim3(768 / 64, MM / 64), 256, 0, stream>>>(
        yc, xz, W_out, b_out, out, MM, 768, D_MODEL, D_MODEL, 768, 768);
}

// Round 2
// 1346.842 us; speedup vs baseline: 1.8845x; 1.8845x over previous
//
#include <hip/hip_runtime.h>
#include <math.h>

#define D_MODEL 768
#define D_STATE 16
#define NGRID   3
#define BB      2
#define LL      2048
#define MM      (BB * LL)   // 4096
#define NC      16          // scan chunks
#define CL      (LL / NC)   // 128 rows per chunk
#define DBLKS   (D_MODEL / 16)   // 48

// ---------------------------------------------------------------------------
// Generic fp32 tiled GEMM: C[M,N] = Atransform(A)[M,K] @ B[K,N] (+ bias)
// MODE 0: plain A
// MODE 1: augmented KAN features from x_norm:  f<768 -> silu(xn[i,f])
//         f>=768 -> kk=f-768, d=kk/3, g=kk%3, phi = exp(-(xn[i,d]-(g-1))^2)
// MODE 2: A = y_core[i,f] * silu(z[i,f]) with z = xz[i, 768+f]
// BM=BN=64, BK=16, 256 threads, 4x4 per thread.
// ---------------------------------------------------------------------------
template<int MODE>
__global__ void gemm_kernel(const float* __restrict__ A,
                            const float* __restrict__ A2,
                            const float* __restrict__ Bm,
                            const float* __restrict__ bias,
                            float* __restrict__ C,
                            int M, int N, int K, int lda, int ldb, int ldc)
{
    const int BM = 64, BN = 64, BK = 16;
    __shared__ float As[BM][BK + 1];
    __shared__ float Bs[BK][BN];

    int tid = threadIdx.x;
    int tx = tid & 15;
    int ty = tid >> 4;
    int row0 = blockIdx.y * BM;
    int col0 = blockIdx.x * BN;

    float acc[4][4] = {};

    for (int k0 = 0; k0 < K; k0 += BK) {
        #pragma unroll
        for (int e = 0; e < 4; ++e) {
            int flat = tid + e * 256;
            int kl = flat & 15;
            int ml = flat >> 4;
            int i = row0 + ml;
            int f = k0 + kl;
            float v;
            if (MODE == 0) {
                v = A[(size_t)i * lda + f];
            } else if (MODE == 1) {
                if (f < D_MODEL) {
                    float xv = A[(size_t)i * D_MODEL + f];
                    v = xv / (1.0f + __expf(-xv));
                } else {
                    int kk = f - D_MODEL;
                    int d  = kk / 3;
                    int g  = kk - d * 3;
                    float xv = A[(size_t)i * D_MODEL + d];
                    float t  = xv - (float)(g - 1);
                    v = __expf(-t * t);
                }
            } else {
                float yv = A[(size_t)i * D_MODEL + f];
                float zv = A2[(size_t)i * (2 * D_MODEL) + D_MODEL + f];
                v = yv * (zv / (1.0f + __expf(-zv)));
            }
            As[ml][kl] = v;
        }
        #pragma unroll
        for (int e = 0; e < 4; ++e) {
            int flat = tid + e * 256;
            int nl = flat & 63;
            int kl = flat >> 6;
            int col = col0 + nl;
            Bs[kl][nl] = (col < N) ? Bm[(size_t)(k0 + kl) * ldb + col] : 0.0f;
        }
        __syncthreads();

        #pragma unroll
        for (int k = 0; k < BK; ++k) {
            float a[4], b[4];
            #pragma unroll
            for (int i2 = 0; i2 < 4; ++i2) a[i2] = As[ty * 4 + i2][k];
            #pragma unroll
            for (int j = 0; j < 4; ++j)    b[j] = Bs[k][tx * 4 + j];
            #pragma unroll
            for (int i2 = 0; i2 < 4; ++i2)
                #pragma unroll
                for (int j = 0; j < 4; ++j)
                    acc[i2][j] += a[i2] * b[j];
        }
        __syncthreads();
    }

    #pragma unroll
    for (int i2 = 0; i2 < 4; ++i2) {
        int row = row0 + ty * 4 + i2;
        #pragma unroll
        for (int j = 0; j < 4; ++j) {
            int col = col0 + tx * 4 + j;
            if (col < N) {
                float bv = bias ? bias[col] : 0.0f;
                C[(size_t)row * ldc + col] = acc[i2][j] + bv;
            }
        }
    }
}

// ---------------------------------------------------------------------------
// LayerNorm over x_proj = xz[:, 0:768] -> x_norm [M, 768]
// ---------------------------------------------------------------------------
__global__ void ln_kernel(const float* __restrict__ xz,
                          const float* __restrict__ gamma,
                          const float* __restrict__ beta,
                          float* __restrict__ xn)
{
    int row = blockIdx.x;
    const float* xp = xz + (size_t)row * (2 * D_MODEL);
    int tid  = threadIdx.x;
    int lane = tid & 63, wave = tid >> 6;

    float v[3];
    float s = 0.f, s2 = 0.f;
    #pragma unroll
    for (int e = 0; e < 3; ++e) {
        v[e] = xp[tid + e * 256];
        s  += v[e];
        s2 += v[e] * v[e];
    }
    #pragma unroll
    for (int off = 32; off >= 1; off >>= 1) {
        s  += __shfl_xor(s,  off);
        s2 += __shfl_xor(s2, off);
    }
    __shared__ float red[2][4];
    if (lane == 0) { red[0][wave] = s; red[1][wave] = s2; }
    __syncthreads();
    s  = red[0][0] + red[0][1] + red[0][2] + red[0][3];
    s2 = red[1][0] + red[1][1] + red[1][2] + red[1][3];

    const float inv = 1.0f / (float)D_MODEL;
    float mean = s * inv;
    float var  = s2 * inv - mean * mean;
    float rstd = rsqrtf(var + 1e-5f);

    #pragma unroll
    for (int e = 0; e < 3; ++e) {
        int c = tid + e * 256;
        xn[(size_t)row * D_MODEL + c] = (v[e] - mean) * rstd * gamma[c] + beta[c];
    }
}

// ---------------------------------------------------------------------------
// Repack the six KAN weight arrays into W_cat [3072, 800]
// ---------------------------------------------------------------------------
__global__ void repack_kernel(const float* __restrict__ kd_b, const float* __restrict__ kd_s,
                              const float* __restrict__ kb_b, const float* __restrict__ kb_s,
                              const float* __restrict__ kc_b, const float* __restrict__ kc_s,
                              float* __restrict__ Wcat)
{
    int idx = blockIdx.x * 256 + threadIdx.x;
    if (idx >= 3072 * 800) return;
    int f = idx / 800;
    int o = idx - f * 800;
    float v;
    if (f < D_MODEL) {
        if (o < 768)      v = kd_b[(size_t)f * 768 + o];
        else if (o < 784) v = kb_b[(size_t)f * 16 + (o - 768)];
        else              v = kc_b[(size_t)f * 16 + (o - 784)];
    } else {
        int sidx = f - D_MODEL;
        if (o < 768)      v = kd_s[(size_t)sidx * 768 + o];
        else if (o < 784) v = kb_s[(size_t)sidx * 16 + (o - 768)];
        else              v = kc_s[(size_t)sidx * 16 + (o - 784)];
    }
    Wcat[idx] = v;
}

// ---------------------------------------------------------------------------
// Chunked selective scan.
// S [M, 800] = [pre_delta(768) | B(16) | C(16)]
// Per-step recurrence (per b,d,n):  h = dA*h + delta*Bn*xp
//   delta = softplus(pre_delta[d]) * exp(-prio) ;  dA = exp(delta * Acont[d,n])
//
// Phase 1: grid B*NC*DBLKS blocks; local scan from h=0 over CL rows.
//          store chunkA = prod(dA), chunkH = local h_final   [b,c,d,n]
// Phase 2: 1 thread per (b,d,n); sequential over chunks -> carry[b,c,d,n]
// Phase 3: same grid as phase 1; rescan seeded with carry, fused output:
//          y[row,d] = sum_n Cn*h + D[d]*xp
// thread map (256 thr): wave=tid>>6 (4 d-groups), dsub=(lane>>4), n=lane&15
//          d = dblk*16 + wave*4 + dsub
// ---------------------------------------------------------------------------
__device__ __forceinline__ void scan_decode(int blk, int tid,
                                            int& b, int& c, int& d, int& n)
{
    b = blk / (NC * DBLKS);
    int rem = blk % (NC * DBLKS);
    c = rem / DBLKS;
    int dblk = rem % DBLKS;
    int wave = tid >> 6, lane = tid & 63;
    int dsub = lane >> 4;
    n = lane & 15;
    d = dblk * 16 + wave * 4 + dsub;
}

__global__ void scan_phase1(const float* __restrict__ S,
                            const float* __restrict__ xz,
                            const float* __restrict__ prio,
                            const float* __restrict__ A_log,
                            float* __restrict__ chunkA,
                            float* __restrict__ chunkH)
{
    int b, c, d, n;
    scan_decode(blockIdx.x, threadIdx.x, b, c, d, n);

    float Acont = -expf(A_log[(size_t)d * D_STATE + n]);
    float Aprod = 1.0f;
    float h = 0.0f;

    int l0 = c * CL;
    for (int l = l0; l < l0 + CL; ++l) {
        int row = b * LL + l;
        const float* sr = S + (size_t)row * 800;
        float dpre = sr[d];
        float Bn   = sr[D_MODEL + n];
        float xp   = xz[(size_t)row * (2 * D_MODEL) + d];
        float pr   = prio[row];

        float sp    = (dpre > 20.0f) ? dpre : log1pf(expf(dpre));
        float delta = sp * expf(-pr);
        float dA    = expf(delta * Acont);
        h = dA * h + delta * Bn * xp;
        Aprod *= dA;
    }
    size_t idx = (((size_t)b * NC + c) * D_MODEL + d) * D_STATE + n;
    chunkA[idx] = Aprod;
    chunkH[idx] = h;
}

__global__ void scan_phase2(const float* __restrict__ chunkA,
                            const float* __restrict__ chunkH,
                            float* __restrict__ carry)
{
    int g = blockIdx.x * 256 + threadIdx.x;           // 0 .. B*768*16-1
    if (g >= BB * D_MODEL * D_STATE) return;
    int b = g / (D_MODEL * D_STATE);
    int rem = g % (D_MODEL * D_STATE);                // d*16+n

    float h0 = 0.0f;
    #pragma unroll
    for (int c = 0; c < NC; ++c) {
        size_t idx = (((size_t)b * NC + c) * D_MODEL * D_STATE) + rem;
        carry[idx] = h0;
        h0 = chunkA[idx] * h0 + chunkH[idx];
    }
}

__global__ void scan_phase3(const float* __restrict__ S,
                            const float* __restrict__ xz,
                            const float* __restrict__ prio,
                            const float* __restrict__ A_log,
                            const float* __restrict__ Dp,
                            const float* __restrict__ carry,
                            float* __restrict__ y_core)
{
    int b, c, d, n;
    scan_decode(blockIdx.x, threadIdx.x, b, c, d, n);

    float Acont = -expf(A_log[(size_t)d * D_STATE + n]);
    float Dv = Dp[d];
    float h = carry[(((size_t)b * NC + c) * D_MODEL + d) * D_STATE + n];

    int l0 = c * CL;
    for (int l = l0; l < l0 + CL; ++l) {
        int row = b * LL + l;
        const float* sr = S + (size_t)row * 800;
        float dpre = sr[d];
        float Bn   = sr[D_MODEL + n];
        float Cn   = sr[D_MODEL + 16 + n];
        float xp   = xz[(size_t)row * (2 * D_MODEL) + d];
        float pr   = prio[row];

        float sp    = (dpre > 20.0f) ? dpre : log1pf(expf(dpre));
        float delta = sp * expf(-pr);
        float dA    = expf(delta * Acont);
        h = dA * h + delta * Bn * xp;

        float acc = Cn * h;
        acc += __shfl_xor(acc, 1);
        acc += __shfl_xor(acc, 2);
        acc += __shfl_xor(acc, 4);
        acc += __shfl_xor(acc, 8);
        if (n == 0)
            y_core[(size_t)row * D_MODEL + d] = acc + Dv * xp;
    }
}

// ---------------------------------------------------------------------------
extern "C" void kernel_launch(void* const* d_in, const int* in_sizes, int n_in,
                              void* d_out, int out_size, void* d_ws, size_t ws_size,
                              hipStream_t stream)
{
    const float* x        = (const float*)d_in[0];
    const float* prio     = (const float*)d_in[1];
    const float* W_in     = (const float*)d_in[2];
    const float* b_in     = (const float*)d_in[3];
    const float* ln_g     = (const float*)d_in[4];
    const float* ln_b     = (const float*)d_in[5];
    const float* kd_base  = (const float*)d_in[6];
    const float* kd_spl   = (const float*)d_in[7];
    const float* kb_base  = (const float*)d_in[8];
    const float* kb_spl   = (const float*)d_in[9];
    const float* kc_base  = (const float*)d_in[10];
    const float* kc_spl   = (const float*)d_in[11];
    const float* A_log    = (const float*)d_in[12];
    const float* D_param  = (const float*)d_in[13];
    const float* W_out    = (const float*)d_in[14];
    const float* b_out    = (const float*)d_in[15];
    float* out = (float*)d_out;

    const size_t CSZ = (size_t)BB * NC * D_MODEL * D_STATE;   // 393216

    float* ws   = (float*)d_ws;
    float* xz   = ws;                                   // 4096*1536
    float* xn   = xz + (size_t)MM * 1536;               // 4096*768
    float* Wcat = xn + (size_t)MM * 768;                // 3072*800
    float* S    = Wcat + (size_t)3072 * 800;            // 4096*800
    float* yc   = S + (size_t)MM * 800;                 // 4096*768
    float* cA   = yc + (size_t)MM * 768;                // chunkA
    float* cH   = cA + CSZ;                             // chunkH
    float* cc   = cH + CSZ;                             // carry

    // 1) xz = x @ W_in + b_in          [4096,1536]
    gemm_kernel<0><<<dim3(1536 / 64, MM / 64), 256, 0, stream>>>(
        x, nullptr, W_in, b_in, xz, MM, 1536, D_MODEL, D_MODEL, 1536, 1536);

    // 2) x_norm = LN(x_proj)           [4096,768]
    ln_kernel<<<MM, 256, 0, stream>>>(xz, ln_g, ln_b, xn);

    // 3) W_cat repack                  [3072,800]
    repack_kernel<<<(3072 * 800 + 255) / 256, 256, 0, stream>>>(
        kd_base, kd_spl, kb_base, kb_spl, kc_base, kc_spl, Wcat);

    // 4) S = Aug(x_norm) @ W_cat       [4096,800]
    gemm_kernel<1><<<dim3((800 + 63) / 64, MM / 64), 256, 0, stream>>>(
        xn, nullptr, Wcat, nullptr, S, MM, 800, 3072, D_MODEL, 800, 800);

    // 5) chunked selective scan -> y_core [4096,768]
    scan_phase1<<<BB * NC * DBLKS, 256, 0, stream>>>(S, xz, prio, A_log, cA, cH);
    scan_phase2<<<(BB * D_MODEL * D_STATE + 255) / 256, 256, 0, stream>>>(cA, cH, cc);
    scan_phase3<<<BB * NC * DBLKS, 256, 0, stream>>>(S, xz, prio, A_log, D_param, cc, yc);

    // 6) out = (y_core * silu(z)) @ W_out + b_out
    gemm_kernel<2><<<dim3(768 / 64, MM / 64), 256, 0, stream>>>(
        yc, xz, W_out, b_out, out, MM, 768, D_MODEL, D_MODEL, 768, 768);
}

// Round 7
// 688.355 us; speedup vs baseline: 3.6872x; 1.9566x over previous
//
#include <hip/hip_runtime.h>
#include <math.h>
#include <stdint.h>

#define D_MODEL 768
#define D_STATE 16
#define BB      2
#define LL      2048
#define MM      (BB * LL)   // 4096
#define NC      16          // scan chunks
#define CL      (LL / NC)   // 128 rows per chunk
#define DBLKS   (D_MODEL / 16)   // 48
#define SLD     896         // padded S row stride (800 -> 896 = 7*128)

typedef __attribute__((ext_vector_type(8))) short short8;
typedef __attribute__((ext_vector_type(4))) float f32x4;

__device__ __forceinline__ short f2bf(float f) {
    union { float f; uint32_t u; } v; v.f = f;
    uint32_t r = v.u + 0x7fff + ((v.u >> 16) & 1);   // RNE
    return (short)(r >> 16);
}
__device__ __forceinline__ float silu(float x) {
    return x / (1.0f + __expf(-x));
}

// ---------------------------------------------------------------------------
// bf16 MFMA GEMM: C[M,N] fp32 = A[M,K]bf16 @ B[K,N] (+bias), B given as
// Bt[N,K] bf16 row-major. 128x128 tile, BK=32, 256 thr = 4 waves (2x2),
// each wave 64x64 = 4x4 fragments of 16x16x32.
// Staging: 128 rows x 32 cols = 4096 bf16 per tile -> 2 short8 per thread.
// ---------------------------------------------------------------------------
#define LDK 40   // LDS row stride in bf16 (32 data + 8 pad)

__global__ __launch_bounds__(256)
void gemm_bf16(const short* __restrict__ A,
               const short* __restrict__ Bt,
               const float* __restrict__ bias,
               float* __restrict__ C,
               int M, int N, int K)
{
    __shared__ short As[128 * LDK];
    __shared__ short Bs[128 * LDK];

    int tid  = threadIdx.x;
    int wid  = tid >> 6, lane = tid & 63;
    int wr   = wid >> 1, wc = wid & 1;
    int row0 = blockIdx.y * 128;
    int col0 = blockIdx.x * 128;

    f32x4 acc[4][4] = {};

    int fr = lane & 15;
    int kb = (lane >> 4) * 8;

    for (int k0 = 0; k0 < K; k0 += 32) {
        short8 av[2], bv[2];
        #pragma unroll
        for (int e = 0; e < 2; ++e) {
            int flat = tid + e * 256;         // 0..511
            int r  = flat >> 2;               // 0..127
            int cc = (flat & 3) * 8;          // 0/8/16/24
            av[e] = *(const short8*)(A  + (size_t)(row0 + r) * K + k0 + cc);
            bv[e] = *(const short8*)(Bt + (size_t)(col0 + r) * K + k0 + cc);
        }
        __syncthreads();                      // previous iter's LDS reads done
        #pragma unroll
        for (int e = 0; e < 2; ++e) {
            int flat = tid + e * 256;
            int r  = flat >> 2;
            int cc = (flat & 3) * 8;
            *(short8*)(&As[r * LDK + cc]) = av[e];
            *(short8*)(&Bs[r * LDK + cc]) = bv[e];
        }
        __syncthreads();

        short8 af[4], bf[4];
        #pragma unroll
        for (int m = 0; m < 4; ++m)
            af[m] = *(const short8*)(&As[(wr * 64 + m * 16 + fr) * LDK + kb]);
        #pragma unroll
        for (int n = 0; n < 4; ++n)
            bf[n] = *(const short8*)(&Bs[(wc * 64 + n * 16 + fr) * LDK + kb]);
        #pragma unroll
        for (int m = 0; m < 4; ++m)
            #pragma unroll
            for (int n = 0; n < 4; ++n)
                acc[m][n] = __builtin_amdgcn_mfma_f32_16x16x32_bf16(
                                af[m], bf[n], acc[m][n], 0, 0, 0);
    }

    int rq = lane >> 4;
    #pragma unroll
    for (int m = 0; m < 4; ++m) {
        #pragma unroll
        for (int n = 0; n < 4; ++n) {
            int col = col0 + wc * 64 + n * 16 + fr;
            float bvv = bias ? bias[col] : 0.0f;
            #pragma unroll
            for (int r = 0; r < 4; ++r) {
                int row = row0 + wr * 64 + m * 16 + rq * 4 + r;
                C[(size_t)row * N + col] = acc[m][n][r] + bvv;
            }
        }
    }
}

// ---------------------------------------------------------------------------
// x fp32 -> bf16
// ---------------------------------------------------------------------------
__global__ void convert_kernel(const float* __restrict__ in, short* __restrict__ out, int n)
{
    int i = blockIdx.x * 256 + threadIdx.x;
    if (i < n) out[i] = f2bf(in[i]);
}

// ---------------------------------------------------------------------------
// W [K,N] fp32 -> Wt [N,K] bf16
// ---------------------------------------------------------------------------
__global__ void wtrans_kernel(const float* __restrict__ W, short* __restrict__ Wt, int K, int N)
{
    int idx = blockIdx.x * 256 + threadIdx.x;
    if (idx >= K * N) return;
    int n = idx / K, k = idx - n * K;
    Wt[idx] = f2bf(W[(size_t)k * N + n]);
}

// ---------------------------------------------------------------------------
// WcatT [896][3072] bf16 (rows >= 800 zero)
// o: 0..767 delta, 768..783 B, 784..799 C ; f: 0..767 base d, 768.. spline d*3+g
// ---------------------------------------------------------------------------
__global__ void repackT_kernel(const float* __restrict__ kd_b, const float* __restrict__ kd_s,
                               const float* __restrict__ kb_b, const float* __restrict__ kb_s,
                               const float* __restrict__ kc_b, const float* __restrict__ kc_s,
                               short* __restrict__ WcatT)
{
    int idx = blockIdx.x * 256 + threadIdx.x;
    if (idx >= SLD * 3072) return;
    int o = idx / 3072;
    int f = idx - o * 3072;
    float v;
    if (o >= 800) v = 0.0f;
    else if (f < D_MODEL) {
        if (o < 768)      v = kd_b[(size_t)f * 768 + o];
        else if (o < 784) v = kb_b[(size_t)f * 16 + (o - 768)];
        else              v = kc_b[(size_t)f * 16 + (o - 784)];
    } else {
        int sidx = f - D_MODEL;
        if (o < 768)      v = kd_s[(size_t)sidx * 768 + o];
        else if (o < 784) v = kb_s[(size_t)sidx * 16 + (o - 768)];
        else              v = kc_s[(size_t)sidx * 16 + (o - 784)];
    }
    WcatT[idx] = f2bf(v);
}

// ---------------------------------------------------------------------------
// LayerNorm of x_proj fused with KAN feature augmentation:
// Aug[row, 0:768]      = bf16(silu(xn))
// Aug[row, 768+3d+g]   = bf16(exp(-(xn_d-(g-1))^2))
// ---------------------------------------------------------------------------
__global__ void ln_aug_kernel(const float* __restrict__ xz,
                              const float* __restrict__ gamma,
                              const float* __restrict__ beta,
                              short* __restrict__ Aug)
{
    int row = blockIdx.x;
    const float* xp = xz + (size_t)row * (2 * D_MODEL);
    int tid  = threadIdx.x;
    int lane = tid & 63, wave = tid >> 6;

    float v[3];
    float s = 0.f, s2 = 0.f;
    #pragma unroll
    for (int e = 0; e < 3; ++e) {
        v[e] = xp[tid + e * 256];
        s  += v[e];
        s2 += v[e] * v[e];
    }
    #pragma unroll
    for (int off = 32; off >= 1; off >>= 1) {
        s  += __shfl_xor(s,  off);
        s2 += __shfl_xor(s2, off);
    }
    __shared__ float red[2][4];
    if (lane == 0) { red[0][wave] = s; red[1][wave] = s2; }
    __syncthreads();
    s  = red[0][0] + red[0][1] + red[0][2] + red[0][3];
    s2 = red[1][0] + red[1][1] + red[1][2] + red[1][3];

    const float inv = 1.0f / (float)D_MODEL;
    float mean = s * inv;
    float var  = s2 * inv - mean * mean;
    float rstd = rsqrtf(var + 1e-5f);

    short* ar = Aug + (size_t)row * 3072;
    #pragma unroll
    for (int e = 0; e < 3; ++e) {
        int c = tid + e * 256;
        float xn = (v[e] - mean) * rstd * gamma[c] + beta[c];
        ar[c] = f2bf(silu(xn));
        #pragma unroll
        for (int g = 0; g < 3; ++g) {
            float t = xn - (float)(g - 1);
            ar[768 + 3 * c + g] = f2bf(__expf(-t * t));
        }
    }
}

// ---------------------------------------------------------------------------
// Chunked selective scan (fp32).  S [M, SLD] = [pre_delta(768)|B(16)|C(16)|pad]
// ---------------------------------------------------------------------------
__device__ __forceinline__ void scan_decode(int blk, int tid,
                                            int& b, int& c, int& d, int& n)
{
    b = blk / (NC * DBLKS);
    int rem = blk % (NC * DBLKS);
    c = rem / DBLKS;
    int dblk = rem % DBLKS;
    int wave = tid >> 6, lane = tid & 63;
    int dsub = lane >> 4;
    n = lane & 15;
    d = dblk * 16 + wave * 4 + dsub;
}

__global__ void scan_phase1(const float* __restrict__ S,
                            const float* __restrict__ xz,
                            const float* __restrict__ prio,
                            const float* __restrict__ A_log,
                            float* __restrict__ chunkA,
                            float* __restrict__ chunkH)
{
    int b, c, d, n;
    scan_decode(blockIdx.x, threadIdx.x, b, c, d, n);

    float Acont = -expf(A_log[(size_t)d * D_STATE + n]);
    float Aprod = 1.0f;
    float h = 0.0f;

    int l0 = c * CL;
    for (int l = l0; l < l0 + CL; ++l) {
        int row = b * LL + l;
        const float* sr = S + (size_t)row * SLD;
        float dpre = sr[d];
        float Bn   = sr[D_MODEL + n];
        float xp   = xz[(size_t)row * (2 * D_MODEL) + d];
        float pr   = prio[row];

        float sp    = (dpre > 20.0f) ? dpre : log1pf(expf(dpre));
        float delta = sp * expf(-pr);
        float dA    = expf(delta * Acont);
        h = dA * h + delta * Bn * xp;
        Aprod *= dA;
    }
    size_t idx = (((size_t)b * NC + c) * D_MODEL + d) * D_STATE + n;
    chunkA[idx] = Aprod;
    chunkH[idx] = h;
}

__global__ void scan_phase2(const float* __restrict__ chunkA,
                            const float* __restrict__ chunkH,
                            float* __restrict__ carry)
{
    int g = blockIdx.x * 256 + threadIdx.x;
    if (g >= BB * D_MODEL * D_STATE) return;
    int b = g / (D_MODEL * D_STATE);
    int rem = g % (D_MODEL * D_STATE);

    float h0 = 0.0f;
    #pragma unroll
    for (int c = 0; c < NC; ++c) {
        size_t idx = (((size_t)b * NC + c) * D_MODEL * D_STATE) + rem;
        carry[idx] = h0;
        h0 = chunkA[idx] * h0 + chunkH[idx];
    }
}

__global__ void scan_phase3(const float* __restrict__ S,
                            const float* __restrict__ xz,
                            const float* __restrict__ prio,
                            const float* __restrict__ A_log,
                            const float* __restrict__ Dp,
                            const float* __restrict__ carry,
                            float* __restrict__ y_core)
{
    int b, c, d, n;
    scan_decode(blockIdx.x, threadIdx.x, b, c, d, n);

    float Acont = -expf(A_log[(size_t)d * D_STATE + n]);
    float Dv = Dp[d];
    float h = carry[(((size_t)b * NC + c) * D_MODEL + d) * D_STATE + n];

    int l0 = c * CL;
    for (int l = l0; l < l0 + CL; ++l) {
        int row = b * LL + l;
        const float* sr = S + (size_t)row * SLD;
        float dpre = sr[d];
        float Bn   = sr[D_MODEL + n];
        float Cn   = sr[D_MODEL + 16 + n];
        float xp   = xz[(size_t)row * (2 * D_MODEL) + d];
        float pr   = prio[row];

        float sp    = (dpre > 20.0f) ? dpre : log1pf(expf(dpre));
        float delta = sp * expf(-pr);
        float dA    = expf(delta * Acont);
        h = dA * h + delta * Bn * xp;

        float acc = Cn * h;
        acc += __shfl_xor(acc, 1);
        acc += __shfl_xor(acc, 2);
        acc += __shfl_xor(acc, 4);
        acc += __shfl_xor(acc, 8);
        if (n == 0)
            y_core[(size_t)row * D_MODEL + d] = acc + Dv * xp;
    }
}

// ---------------------------------------------------------------------------
// yg bf16 = y_core * silu(z)
// ---------------------------------------------------------------------------
__global__ void gate_kernel(const float* __restrict__ yc,
                            const float* __restrict__ xz,
                            short* __restrict__ yg)
{
    int idx = blockIdx.x * 256 + threadIdx.x;
    if (idx >= MM * D_MODEL) return;
    int row = idx / D_MODEL;
    int d   = idx - row * D_MODEL;
    float z = xz[(size_t)row * (2 * D_MODEL) + D_MODEL + d];
    yg[idx] = f2bf(yc[idx] * silu(z));
}

// ---------------------------------------------------------------------------
// Workspace layout (float offsets), peak 74.1 MB — temporal reuse:
//   xz   : [0, 6291456)                 live GEMM1..gate
//   S    : [6291456, 9961472)           live GEMM2..scan3
//   AB = 9961472 (25.2MB region):
//     xb  (bf16) @ AB                   live convert..GEMM1
//     Aug (bf16) @ AB                   live ln_aug..GEMM2 (over dead xb)
//     cA/cH/cc/yc @ AB..AB+4325376      live scan1..gate  (over dead Aug)
//     yg (bf16) @ ws+14286848           live gate..GEMM3  (over dead Aug tail)
//   WinT  @ ws+16252928  WcatT @ ws+16842752  WoutT @ ws+18219008
// ---------------------------------------------------------------------------
extern "C" void kernel_launch(void* const* d_in, const int* in_sizes, int n_in,
                              void* d_out, int out_size, void* d_ws, size_t ws_size,
                              hipStream_t stream)
{
    const float* x        = (const float*)d_in[0];
    const float* prio     = (const float*)d_in[1];
    const float* W_in     = (const float*)d_in[2];
    const float* b_in     = (const float*)d_in[3];
    const float* ln_g     = (const float*)d_in[4];
    const float* ln_b     = (const float*)d_in[5];
    const float* kd_base  = (const float*)d_in[6];
    const float* kd_spl   = (const float*)d_in[7];
    const float* kb_base  = (const float*)d_in[8];
    const float* kb_spl   = (const float*)d_in[9];
    const float* kc_base  = (const float*)d_in[10];
    const float* kc_spl   = (const float*)d_in[11];
    const float* A_log    = (const float*)d_in[12];
    const float* D_param  = (const float*)d_in[13];
    const float* W_out    = (const float*)d_in[14];
    const float* b_out    = (const float*)d_in[15];
    float* out = (float*)d_out;

    float* ws    = (float*)d_ws;
    float* xz    = ws;
    float* S     = ws + 6291456;
    float* AB    = ws + 9961472;
    short* xb    = (short*)AB;               // convert..GEMM1
    short* Aug   = (short*)AB;               // ln_aug..GEMM2
    float* cA    = AB;                       // scan1..scan2
    float* cH    = AB + 393216;
    float* cc    = AB + 786432;              // scan2..scan3
    float* yc    = AB + 1179648;             // scan3..gate
    short* yg    = (short*)(ws + 14286848);  // gate..GEMM3
    short* WinT  = (short*)(ws + 16252928);
    short* WcatT = (short*)(ws + 16842752);
    short* WoutT = (short*)(ws + 18219008);

    // --- weight prep + input convert ---
    convert_kernel<<<(MM * D_MODEL + 255) / 256, 256, 0, stream>>>(x, xb, MM * D_MODEL);
    wtrans_kernel<<<(768 * 1536 + 255) / 256, 256, 0, stream>>>(W_in, WinT, 768, 1536);
    repackT_kernel<<<(SLD * 3072 + 255) / 256, 256, 0, stream>>>(
        kd_base, kd_spl, kb_base, kb_spl, kc_base, kc_spl, WcatT);
    wtrans_kernel<<<(768 * 768 + 255) / 256, 256, 0, stream>>>(W_out, WoutT, 768, 768);

    // 1) xz = x @ W_in + b_in          [4096,1536]
    gemm_bf16<<<dim3(1536 / 128, MM / 128), 256, 0, stream>>>(
        xb, WinT, b_in, xz, MM, 1536, 768);

    // 2+3) LN + KAN augmentation -> Aug bf16 [4096,3072]
    ln_aug_kernel<<<MM, 256, 0, stream>>>(xz, ln_g, ln_b, Aug);

    // 4) S = Aug @ W_cat               [4096,896] (cols 800+ are zero)
    gemm_bf16<<<dim3(SLD / 128, MM / 128), 256, 0, stream>>>(
        Aug, WcatT, nullptr, S, MM, SLD, 3072);

    // 5) chunked selective scan -> y_core
    scan_phase1<<<BB * NC * DBLKS, 256, 0, stream>>>(S, xz, prio, A_log, cA, cH);
    scan_phase2<<<(BB * D_MODEL * D_STATE + 255) / 256, 256, 0, stream>>>(cA, cH, cc);
    scan_phase3<<<BB * NC * DBLKS, 256, 0, stream>>>(S, xz, prio, A_log, D_param, cc, yc);

    // 6) yg = y_core * silu(z)
    gate_kernel<<<(MM * D_MODEL + 255) / 256, 256, 0, stream>>>(yc, xz, yg);

    // 7) out = yg @ W_out + b_out      [4096,768]
    gemm_bf16<<<dim3(768 / 128, MM / 128), 256, 0, stream>>>(
        yg, WoutT, b_out, out, MM, 768, 768);
}

// Round 12
// 339.899 us; speedup vs baseline: 7.4673x; 2.0252x over previous
//
#include <hip/hip_runtime.h>
#include <math.h>
#include <stdint.h>

#define D_MODEL 768
#define D_STATE 16
#define BB      2
#define LL      2048
#define MM      (BB * LL)   // 4096
#define NC      64          // scan chunks
#define CL      (LL / NC)   // 32 rows per chunk
#define SLD     896         // padded S row stride (800 -> 896)

typedef __attribute__((ext_vector_type(8))) short short8;
typedef __attribute__((ext_vector_type(4))) float f32x4;

__device__ __forceinline__ short f2bf(float f) {
    union { float f; uint32_t u; } v; v.f = f;
    uint32_t r = v.u + 0x7fff + ((v.u >> 16) & 1);   // RNE
    return (short)(r >> 16);
}
__device__ __forceinline__ float silu(float x) {
    return x / (1.0f + __expf(-x));
}

// ---------------------------------------------------------------------------
// bf16 MFMA GEMM: C[M,N] fp32 = A[M,K]bf16 @ Bt[N,K]bf16 (+bias).
// If prio != null: cols < 768 get the delta transform
//   C = softplus(acc) * exp(-prio[row])    (fused for the scan)
// 128x128 tile, BK=32, 256 thr = 4 waves (2x2), 4x4 frags of 16x16x32.
// ---------------------------------------------------------------------------
#define LDK 40   // LDS row stride in bf16 (32 data + 8 pad)

__global__ __launch_bounds__(256)
void gemm_bf16(const short* __restrict__ A,
               const short* __restrict__ Bt,
               const float* __restrict__ bias,
               const float* __restrict__ prio,
               float* __restrict__ C,
               int M, int N, int K)
{
    __shared__ short As[128 * LDK];
    __shared__ short Bs[128 * LDK];

    int tid  = threadIdx.x;
    int wid  = tid >> 6, lane = tid & 63;
    int wr   = wid >> 1, wc = wid & 1;
    int row0 = blockIdx.y * 128;
    int col0 = blockIdx.x * 128;

    f32x4 acc[4][4] = {};

    int fr = lane & 15;
    int kb = (lane >> 4) * 8;

    for (int k0 = 0; k0 < K; k0 += 32) {
        short8 av[2], bv[2];
        #pragma unroll
        for (int e = 0; e < 2; ++e) {
            int flat = tid + e * 256;         // 0..511
            int r  = flat >> 2;               // 0..127
            int cc = (flat & 3) * 8;          // 0/8/16/24
            av[e] = *(const short8*)(A  + (size_t)(row0 + r) * K + k0 + cc);
            bv[e] = *(const short8*)(Bt + (size_t)(col0 + r) * K + k0 + cc);
        }
        __syncthreads();
        #pragma unroll
        for (int e = 0; e < 2; ++e) {
            int flat = tid + e * 256;
            int r  = flat >> 2;
            int cc = (flat & 3) * 8;
            *(short8*)(&As[r * LDK + cc]) = av[e];
            *(short8*)(&Bs[r * LDK + cc]) = bv[e];
        }
        __syncthreads();

        short8 af[4], bf[4];
        #pragma unroll
        for (int m = 0; m < 4; ++m)
            af[m] = *(const short8*)(&As[(wr * 64 + m * 16 + fr) * LDK + kb]);
        #pragma unroll
        for (int n = 0; n < 4; ++n)
            bf[n] = *(const short8*)(&Bs[(wc * 64 + n * 16 + fr) * LDK + kb]);
        #pragma unroll
        for (int m = 0; m < 4; ++m)
            #pragma unroll
            for (int n = 0; n < 4; ++n)
                acc[m][n] = __builtin_amdgcn_mfma_f32_16x16x32_bf16(
                                af[m], bf[n], acc[m][n], 0, 0, 0);
    }

    int rq = lane >> 4;
    #pragma unroll
    for (int m = 0; m < 4; ++m) {
        #pragma unroll
        for (int n = 0; n < 4; ++n) {
            int col = col0 + wc * 64 + n * 16 + fr;
            float bvv = bias ? bias[col] : 0.0f;
            #pragma unroll
            for (int r = 0; r < 4; ++r) {
                int row = row0 + wr * 64 + m * 16 + rq * 4 + r;
                float v = acc[m][n][r] + bvv;
                if (prio && col < D_MODEL) {
                    float sp = (v > 20.0f) ? v : log1pf(__expf(v));
                    v = sp * __expf(-prio[row]);
                }
                C[(size_t)row * N + col] = v;
            }
        }
    }
}

// ---------------------------------------------------------------------------
__global__ void convert_kernel(const float* __restrict__ in, short* __restrict__ out, int n)
{
    int i = blockIdx.x * 256 + threadIdx.x;
    if (i < n) out[i] = f2bf(in[i]);
}

__global__ void wtrans_kernel(const float* __restrict__ W, short* __restrict__ Wt, int K, int N)
{
    int idx = blockIdx.x * 256 + threadIdx.x;
    if (idx >= K * N) return;
    int n = idx / K, k = idx - n * K;
    Wt[idx] = f2bf(W[(size_t)k * N + n]);
}

// ---------------------------------------------------------------------------
// WcatT [896][3072] bf16 (rows >= 800 zero)
// ---------------------------------------------------------------------------
__global__ void repackT_kernel(const float* __restrict__ kd_b, const float* __restrict__ kd_s,
                               const float* __restrict__ kb_b, const float* __restrict__ kb_s,
                               const float* __restrict__ kc_b, const float* __restrict__ kc_s,
                               short* __restrict__ WcatT)
{
    int idx = blockIdx.x * 256 + threadIdx.x;
    if (idx >= SLD * 3072) return;
    int o = idx / 3072;
    int f = idx - o * 3072;
    float v;
    if (o >= 800) v = 0.0f;
    else if (f < D_MODEL) {
        if (o < 768)      v = kd_b[(size_t)f * 768 + o];
        else if (o < 784) v = kb_b[(size_t)f * 16 + (o - 768)];
        else              v = kc_b[(size_t)f * 16 + (o - 784)];
    } else {
        int sidx = f - D_MODEL;
        if (o < 768)      v = kd_s[(size_t)sidx * 768 + o];
        else if (o < 784) v = kb_s[(size_t)sidx * 16 + (o - 768)];
        else              v = kc_s[(size_t)sidx * 16 + (o - 784)];
    }
    WcatT[idx] = f2bf(v);
}

// ---------------------------------------------------------------------------
// LayerNorm + KAN augmentation -> Aug bf16 [4096,3072]
// ---------------------------------------------------------------------------
__global__ void ln_aug_kernel(const float* __restrict__ xz,
                              const float* __restrict__ gamma,
                              const float* __restrict__ beta,
                              short* __restrict__ Aug)
{
    int row = blockIdx.x;
    const float* xp = xz + (size_t)row * (2 * D_MODEL);
    int tid  = threadIdx.x;
    int lane = tid & 63, wave = tid >> 6;

    float v[3];
    float s = 0.f, s2 = 0.f;
    #pragma unroll
    for (int e = 0; e < 3; ++e) {
        v[e] = xp[tid + e * 256];
        s  += v[e];
        s2 += v[e] * v[e];
    }
    #pragma unroll
    for (int off = 32; off >= 1; off >>= 1) {
        s  += __shfl_xor(s,  off);
        s2 += __shfl_xor(s2, off);
    }
    __shared__ float red[2][4];
    if (lane == 0) { red[0][wave] = s; red[1][wave] = s2; }
    __syncthreads();
    s  = red[0][0] + red[0][1] + red[0][2] + red[0][3];
    s2 = red[1][0] + red[1][1] + red[1][2] + red[1][3];

    const float inv = 1.0f / (float)D_MODEL;
    float mean = s * inv;
    float var  = s2 * inv - mean * mean;
    float rstd = rsqrtf(var + 1e-5f);

    short* ar = Aug + (size_t)row * 3072;
    #pragma unroll
    for (int e = 0; e < 3; ++e) {
        int c = tid + e * 256;
        float xn = (v[e] - mean) * rstd * gamma[c] + beta[c];
        ar[c] = f2bf(silu(xn));
        #pragma unroll
        for (int g = 0; g < 3; ++g) {
            float t = xn - (float)(g - 1);
            ar[768 + 3 * c + g] = f2bf(__expf(-t * t));
        }
    }
}

// ---------------------------------------------------------------------------
// Chunked selective scan, one thread per (b,chunk,d), n=0..15 in registers.
// S row = [delta(768, pre-transformed) | B(16) | C(16) | pad]
// chunk arrays layout [b, c, n, d]  (coalesced in d)
// ---------------------------------------------------------------------------
__global__ __launch_bounds__(256)
void scan_phase1(const float* __restrict__ S,
                 const float* __restrict__ xz,
                 const float* __restrict__ A_log,
                 float* __restrict__ chunkA,
                 float* __restrict__ chunkH)
{
    int blk  = blockIdx.x;                 // b*(NC*3) + c*3 + dblk
    int b    = blk / (NC * 3);
    int rem  = blk % (NC * 3);
    int c    = rem / 3;
    int dblk = rem % 3;
    int d    = dblk * 256 + threadIdx.x;

    float Ac[16], h[16], P[16];
    #pragma unroll
    for (int n = 0; n < 16; ++n) {
        Ac[n] = -__expf(A_log[(size_t)d * 16 + n]);
        h[n] = 0.0f;
        P[n] = 1.0f;
    }

    int l0 = c * CL;
    for (int l = 0; l < CL; ++l) {
        int row = b * LL + l0 + l;
        const float* sr = S + (size_t)row * SLD;
        float delta = sr[d];
        float xp    = xz[(size_t)row * 1536 + d];
        float bx    = delta * xp;
        float4 B0 = *(const float4*)(sr + 768);
        float4 B1 = *(const float4*)(sr + 772);
        float4 B2 = *(const float4*)(sr + 776);
        float4 B3 = *(const float4*)(sr + 780);
        float Bv[16] = {B0.x,B0.y,B0.z,B0.w, B1.x,B1.y,B1.z,B1.w,
                        B2.x,B2.y,B2.z,B2.w, B3.x,B3.y,B3.z,B3.w};
        #pragma unroll
        for (int n = 0; n < 16; ++n) {
            float dA = __expf(delta * Ac[n]);
            h[n] = dA * h[n] + bx * Bv[n];
            P[n] *= dA;
        }
    }

    size_t base = (size_t)(b * NC + c) * (16 * 768) + d;
    #pragma unroll
    for (int n = 0; n < 16; ++n) {
        chunkA[base + n * 768] = P[n];
        chunkH[base + n * 768] = h[n];
    }
}

__global__ void scan_phase2(const float* __restrict__ chunkA,
                            const float* __restrict__ chunkH,
                            float* __restrict__ carry)
{
    int g = blockIdx.x * 256 + threadIdx.x;          // 0 .. B*16*768-1
    if (g >= BB * 16 * 768) return;
    int b  = g / (16 * 768);
    int nd = g % (16 * 768);

    float h0 = 0.0f;
    for (int c = 0; c < NC; ++c) {
        size_t idx = (size_t)(b * NC + c) * (16 * 768) + nd;
        float a = chunkA[idx];
        float hh = chunkH[idx];
        carry[idx] = h0;
        h0 = a * h0 + hh;
    }
}

__global__ __launch_bounds__(256)
void scan_phase3(const float* __restrict__ S,
                 const float* __restrict__ xz,
                 const float* __restrict__ A_log,
                 const float* __restrict__ Dp,
                 const float* __restrict__ carry,
                 short* __restrict__ yg)       // bf16 out: y_core * silu(z)
{
    int blk  = blockIdx.x;
    int b    = blk / (NC * 3);
    int rem  = blk % (NC * 3);
    int c    = rem / 3;
    int dblk = rem % 3;
    int d    = dblk * 256 + threadIdx.x;

    float Ac[16], h[16];
    size_t base = (size_t)(b * NC + c) * (16 * 768) + d;
    #pragma unroll
    for (int n = 0; n < 16; ++n) {
        Ac[n] = -__expf(A_log[(size_t)d * 16 + n]);
        h[n]  = carry[base + n * 768];
    }
    float Dv = Dp[d];

    int l0 = c * CL;
    for (int l = 0; l < CL; ++l) {
        int row = b * LL + l0 + l;
        const float* sr = S + (size_t)row * SLD;
        float delta = sr[d];
        float xp    = xz[(size_t)row * 1536 + d];
        float bx    = delta * xp;
        float4 B0 = *(const float4*)(sr + 768);
        float4 B1 = *(const float4*)(sr + 772);
        float4 B2 = *(const float4*)(sr + 776);
        float4 B3 = *(const float4*)(sr + 780);
        float4 C0 = *(const float4*)(sr + 784);
        float4 C1 = *(const float4*)(sr + 788);
        float4 C2 = *(const float4*)(sr + 792);
        float4 C3 = *(const float4*)(sr + 796);
        float Bv[16] = {B0.x,B0.y,B0.z,B0.w, B1.x,B1.y,B1.z,B1.w,
                        B2.x,B2.y,B2.z,B2.w, B3.x,B3.y,B3.z,B3.w};
        float Cv[16] = {C0.x,C0.y,C0.z,C0.w, C1.x,C1.y,C1.z,C1.w,
                        C2.x,C2.y,C2.z,C2.w, C3.x,C3.y,C3.z,C3.w};

        float acc = Dv * xp;
        #pragma unroll
        for (int n = 0; n < 16; ++n) {
            float dA = __expf(delta * Ac[n]);
            h[n] = dA * h[n] + bx * Bv[n];
            acc += Cv[n] * h[n];
        }
        float z = xz[(size_t)row * 1536 + 768 + d];
        yg[(size_t)row * 768 + d] = f2bf(acc * silu(z));
    }
}

// ---------------------------------------------------------------------------
// Workspace layout (float offsets), peak 74.1 MB — temporal reuse:
//   xz : [0, 6291456)                live GEMM1..scan3
//   S  : [6291456, 9961472)          live GEMM2..scan3
//   AB = 9961472 (region of 6291456 floats = dead-Aug reuse):
//     xb  (bf16) @AB                 live convert..GEMM1
//     Aug (bf16) @AB                 live ln_aug..GEMM2
//     cA @AB+0        (1572864 f)    live scan1..scan2
//     cH @AB+1572864  (1572864 f)    live scan1..scan2
//     cc @AB+3145728  (1572864 f)    live scan2..scan3
//     yg (bf16) @AB+4718592          live scan3..GEMM3   (ends AB+5505024 < AB+6291456)
//   WinT @16252928  WcatT @16842752  WoutT @18219008  (end 18513920 f = 74.1MB)
// ---------------------------------------------------------------------------
extern "C" void kernel_launch(void* const* d_in, const int* in_sizes, int n_in,
                              void* d_out, int out_size, void* d_ws, size_t ws_size,
                              hipStream_t stream)
{
    const float* x        = (const float*)d_in[0];
    const float* prio     = (const float*)d_in[1];
    const float* W_in     = (const float*)d_in[2];
    const float* b_in     = (const float*)d_in[3];
    const float* ln_g     = (const float*)d_in[4];
    const float* ln_b     = (const float*)d_in[5];
    const float* kd_base  = (const float*)d_in[6];
    const float* kd_spl   = (const float*)d_in[7];
    const float* kb_base  = (const float*)d_in[8];
    const float* kb_spl   = (const float*)d_in[9];
    const float* kc_base  = (const float*)d_in[10];
    const float* kc_spl   = (const float*)d_in[11];
    const float* A_log    = (const float*)d_in[12];
    const float* D_param  = (const float*)d_in[13];
    const float* W_out    = (const float*)d_in[14];
    const float* b_out    = (const float*)d_in[15];
    float* out = (float*)d_out;

    float* ws    = (float*)d_ws;
    float* xz    = ws;
    float* S     = ws + 6291456;
    float* AB    = ws + 9961472;
    short* xb    = (short*)AB;                 // convert..GEMM1
    short* Aug   = (short*)AB;                 // ln_aug..GEMM2
    float* cA    = AB;                         // scan1..scan2
    float* cH    = AB + 1572864;
    float* cc    = AB + 3145728;               // scan2..scan3
    short* yg    = (short*)(AB + 4718592);     // scan3..GEMM3
    short* WinT  = (short*)(ws + 16252928);
    short* WcatT = (short*)(ws + 16842752);
    short* WoutT = (short*)(ws + 18219008);

    // --- weight prep + input convert ---
    convert_kernel<<<(MM * D_MODEL + 255) / 256, 256, 0, stream>>>(x, xb, MM * D_MODEL);
    wtrans_kernel<<<(768 * 1536 + 255) / 256, 256, 0, stream>>>(W_in, WinT, 768, 1536);
    repackT_kernel<<<(SLD * 3072 + 255) / 256, 256, 0, stream>>>(
        kd_base, kd_spl, kb_base, kb_spl, kc_base, kc_spl, WcatT);
    wtrans_kernel<<<(768 * 768 + 255) / 256, 256, 0, stream>>>(W_out, WoutT, 768, 768);

    // 1) xz = x @ W_in + b_in          [4096,1536]
    gemm_bf16<<<dim3(1536 / 128, MM / 128), 256, 0, stream>>>(
        xb, WinT, b_in, nullptr, xz, MM, 1536, 768);

    // 2+3) LN + KAN augmentation -> Aug bf16 [4096,3072]
    ln_aug_kernel<<<MM, 256, 0, stream>>>(xz, ln_g, ln_b, Aug);

    // 4) S = Aug @ W_cat, delta-transform fused for cols<768   [4096,896]
    gemm_bf16<<<dim3(SLD / 128, MM / 128), 256, 0, stream>>>(
        Aug, WcatT, nullptr, prio, S, MM, SLD, 3072);

    // 5) chunked selective scan (gate fused into phase3 -> yg bf16)
    scan_phase1<<<BB * NC * 3, 256, 0, stream>>>(S, xz, A_log, cA, cH);
    scan_phase2<<<(BB * 16 * 768 + 255) / 256, 256, 0, stream>>>(cA, cH, cc);
    scan_phase3<<<BB * NC * 3, 256, 0, stream>>>(S, xz, A_log, D_param, cc, yg);

    // 6) out = yg @ W_out + b_out      [4096,768]
    gemm_bf16<<<dim3(768 / 128, MM / 128), 256, 0, stream>>>(
        yg, WoutT, b_out, nullptr, out, MM, 768, 768);
}

// Round 13
// 306.579 us; speedup vs baseline: 8.2789x; 1.1087x over previous
//
#include <hip/hip_runtime.h>
#include <math.h>
#include <stdint.h>

#define D_MODEL 768
#define D_STATE 16
#define BB      2
#define LL      2048
#define MM      (BB * LL)   // 4096
#define NC      64          // scan chunks
#define CL      (LL / NC)   // 32 rows per chunk
#define SLD     896         // padded S row stride (800 -> 896)

typedef __attribute__((ext_vector_type(8))) short short8;
typedef __attribute__((ext_vector_type(4))) float f32x4;

__device__ __forceinline__ short f2bf(float f) {
    union { float f; uint32_t u; } v; v.f = f;
    uint32_t r = v.u + 0x7fff + ((v.u >> 16) & 1);   // RNE
    return (short)(r >> 16);
}
__device__ __forceinline__ float silu(float x) {
    return x / (1.0f + __expf(-x));
}

// ---------------------------------------------------------------------------
// bf16 MFMA GEMM: C[M,N] fp32 = A[M,K]bf16 @ Bt[N,K]bf16 (+bias).
// If prio != null: cols < 768 get C = softplus(acc)*exp(-prio[row]).
// 64x64 tile, BK=32, 256 thr = 4 waves (2x2), each wave 32x32 (2x2 frags).
// Staging via global_load_lds (16B/lane, linear LDS, m97 pattern):
//   wave w stages rows [w*16, w*16+16) of the 64x32 tile (1 KB slab).
// Grid: (N/64, M/64) -> >=768 blocks for all three GEMMs => 3-6 blocks/CU
// co-resident, hiding the per-K-step barrier drain (m114 overlap).
// ---------------------------------------------------------------------------
__global__ __launch_bounds__(256)
void gemm_bf16(const short* __restrict__ A,
               const short* __restrict__ Bt,
               const float* __restrict__ bias,
               const float* __restrict__ prio,
               float* __restrict__ C,
               int M, int N, int K)
{
    __shared__ short As[64 * 32];
    __shared__ short Bs[64 * 32];

    int tid  = threadIdx.x;
    int wid  = tid >> 6, lane = tid & 63;
    int wr   = wid >> 1, wc = wid & 1;
    int row0 = blockIdx.y * 64;
    int col0 = blockIdx.x * 64;

    // staging map: lane -> (row sr_, col sc_) of the 64x32 tile
    int sr_ = wid * 16 + (lane >> 2);          // 0..63
    int sc_ = (lane & 3) * 8;                  // 0/8/16/24
    const short* gA = A  + (size_t)(row0 + sr_) * K + sc_;
    const short* gB = Bt + (size_t)(col0 + sr_) * K + sc_;
    short* lA = As + wid * 512;                // wave-uniform slab base
    short* lB = Bs + wid * 512;

    int fr = lane & 15;
    int kg = lane >> 4;                        // k-octet select
    f32x4 acc[2][2] = {};

    for (int k0 = 0; k0 < K; k0 += 32) {
        __syncthreads();   // prior iter's ds_reads done before overwrite
        __builtin_amdgcn_global_load_lds(
            (const __attribute__((address_space(1))) void*)(gA + k0),
            (__attribute__((address_space(3))) void*)lA, 16, 0, 0);
        __builtin_amdgcn_global_load_lds(
            (const __attribute__((address_space(1))) void*)(gB + k0),
            (__attribute__((address_space(3))) void*)lB, 16, 0, 0);
        __syncthreads();   // compiler drains vmcnt(0) here -> LDS ready

        short8 af0 = *(const short8*)(&As[(wr * 32 +      fr) * 32 + kg * 8]);
        short8 af1 = *(const short8*)(&As[(wr * 32 + 16 + fr) * 32 + kg * 8]);
        short8 bf0 = *(const short8*)(&Bs[(wc * 32 +      fr) * 32 + kg * 8]);
        short8 bf1 = *(const short8*)(&Bs[(wc * 32 + 16 + fr) * 32 + kg * 8]);

        acc[0][0] = __builtin_amdgcn_mfma_f32_16x16x32_bf16(af0, bf0, acc[0][0], 0, 0, 0);
        acc[0][1] = __builtin_amdgcn_mfma_f32_16x16x32_bf16(af0, bf1, acc[0][1], 0, 0, 0);
        acc[1][0] = __builtin_amdgcn_mfma_f32_16x16x32_bf16(af1, bf0, acc[1][0], 0, 0, 0);
        acc[1][1] = __builtin_amdgcn_mfma_f32_16x16x32_bf16(af1, bf1, acc[1][1], 0, 0, 0);
    }

    int rq = lane >> 4;
    #pragma unroll
    for (int m = 0; m < 2; ++m) {
        #pragma unroll
        for (int n = 0; n < 2; ++n) {
            int col = col0 + wc * 32 + n * 16 + fr;
            float bvv = bias ? bias[col] : 0.0f;
            #pragma unroll
            for (int r = 0; r < 4; ++r) {
                int row = row0 + wr * 32 + m * 16 + rq * 4 + r;
                float v = acc[m][n][r] + bvv;
                if (prio && col < D_MODEL) {
                    float sp = (v > 20.0f) ? v : log1pf(__expf(v));
                    v = sp * __expf(-prio[row]);
                }
                C[(size_t)row * N + col] = v;
            }
        }
    }
}

// ---------------------------------------------------------------------------
__global__ void convert_kernel(const float* __restrict__ in, short* __restrict__ out, int n)
{
    int i = blockIdx.x * 256 + threadIdx.x;
    if (i < n) out[i] = f2bf(in[i]);
}

__global__ void wtrans_kernel(const float* __restrict__ W, short* __restrict__ Wt, int K, int N)
{
    int idx = blockIdx.x * 256 + threadIdx.x;
    if (idx >= K * N) return;
    int n = idx / K, k = idx - n * K;
    Wt[idx] = f2bf(W[(size_t)k * N + n]);
}

// ---------------------------------------------------------------------------
// WcatT [896][3072] bf16 (rows >= 800 zero)
// ---------------------------------------------------------------------------
__global__ void repackT_kernel(const float* __restrict__ kd_b, const float* __restrict__ kd_s,
                               const float* __restrict__ kb_b, const float* __restrict__ kb_s,
                               const float* __restrict__ kc_b, const float* __restrict__ kc_s,
                               short* __restrict__ WcatT)
{
    int idx = blockIdx.x * 256 + threadIdx.x;
    if (idx >= SLD * 3072) return;
    int o = idx / 3072;
    int f = idx - o * 3072;
    float v;
    if (o >= 800) v = 0.0f;
    else if (f < D_MODEL) {
        if (o < 768)      v = kd_b[(size_t)f * 768 + o];
        else if (o < 784) v = kb_b[(size_t)f * 16 + (o - 768)];
        else              v = kc_b[(size_t)f * 16 + (o - 784)];
    } else {
        int sidx = f - D_MODEL;
        if (o < 768)      v = kd_s[(size_t)sidx * 768 + o];
        else if (o < 784) v = kb_s[(size_t)sidx * 16 + (o - 768)];
        else              v = kc_s[(size_t)sidx * 16 + (o - 784)];
    }
    WcatT[idx] = f2bf(v);
}

// ---------------------------------------------------------------------------
// LayerNorm + KAN augmentation -> Aug bf16 [4096,3072]
// ---------------------------------------------------------------------------
__global__ void ln_aug_kernel(const float* __restrict__ xz,
                              const float* __restrict__ gamma,
                              const float* __restrict__ beta,
                              short* __restrict__ Aug)
{
    int row = blockIdx.x;
    const float* xp = xz + (size_t)row * (2 * D_MODEL);
    int tid  = threadIdx.x;
    int lane = tid & 63, wave = tid >> 6;

    float v[3];
    float s = 0.f, s2 = 0.f;
    #pragma unroll
    for (int e = 0; e < 3; ++e) {
        v[e] = xp[tid + e * 256];
        s  += v[e];
        s2 += v[e] * v[e];
    }
    #pragma unroll
    for (int off = 32; off >= 1; off >>= 1) {
        s  += __shfl_xor(s,  off);
        s2 += __shfl_xor(s2, off);
    }
    __shared__ float red[2][4];
    if (lane == 0) { red[0][wave] = s; red[1][wave] = s2; }
    __syncthreads();
    s  = red[0][0] + red[0][1] + red[0][2] + red[0][3];
    s2 = red[1][0] + red[1][1] + red[1][2] + red[1][3];

    const float inv = 1.0f / (float)D_MODEL;
    float mean = s * inv;
    float var  = s2 * inv - mean * mean;
    float rstd = rsqrtf(var + 1e-5f);

    short* ar = Aug + (size_t)row * 3072;
    #pragma unroll
    for (int e = 0; e < 3; ++e) {
        int c = tid + e * 256;
        float xn = (v[e] - mean) * rstd * gamma[c] + beta[c];
        ar[c] = f2bf(silu(xn));
        #pragma unroll
        for (int g = 0; g < 3; ++g) {
            float t = xn - (float)(g - 1);
            ar[768 + 3 * c + g] = f2bf(__expf(-t * t));
        }
    }
}

// ---------------------------------------------------------------------------
// Chunked selective scan, one thread per (b,chunk,d), n=0..15 in registers.
// S row = [delta(768, pre-transformed) | B(16) | C(16) | pad]
// chunk arrays layout [b, c, n, d]  (coalesced in d)
// ---------------------------------------------------------------------------
__global__ __launch_bounds__(256)
void scan_phase1(const float* __restrict__ S,
                 const float* __restrict__ xz,
                 const float* __restrict__ A_log,
                 float* __restrict__ chunkA,
                 float* __restrict__ chunkH)
{
    int blk  = blockIdx.x;                 // b*(NC*3) + c*3 + dblk
    int b    = blk / (NC * 3);
    int rem  = blk % (NC * 3);
    int c    = rem / 3;
    int dblk = rem % 3;
    int d    = dblk * 256 + threadIdx.x;

    float Ac[16], h[16], P[16];
    #pragma unroll
    for (int n = 0; n < 16; ++n) {
        Ac[n] = -__expf(A_log[(size_t)d * 16 + n]);
        h[n] = 0.0f;
        P[n] = 1.0f;
    }

    int l0 = c * CL;
    for (int l = 0; l < CL; ++l) {
        int row = b * LL + l0 + l;
        const float* sr = S + (size_t)row * SLD;
        float delta = sr[d];
        float xp    = xz[(size_t)row * 1536 + d];
        float bx    = delta * xp;
        float4 B0 = *(const float4*)(sr + 768);
        float4 B1 = *(const float4*)(sr + 772);
        float4 B2 = *(const float4*)(sr + 776);
        float4 B3 = *(const float4*)(sr + 780);
        float Bv[16] = {B0.x,B0.y,B0.z,B0.w, B1.x,B1.y,B1.z,B1.w,
                        B2.x,B2.y,B2.z,B2.w, B3.x,B3.y,B3.z,B3.w};
        #pragma unroll
        for (int n = 0; n < 16; ++n) {
            float dA = __expf(delta * Ac[n]);
            h[n] = dA * h[n] + bx * Bv[n];
            P[n] *= dA;
        }
    }

    size_t base = (size_t)(b * NC + c) * (16 * 768) + d;
    #pragma unroll
    for (int n = 0; n < 16; ++n) {
        chunkA[base + n * 768] = P[n];
        chunkH[base + n * 768] = h[n];
    }
}

__global__ void scan_phase2(const float* __restrict__ chunkA,
                            const float* __restrict__ chunkH,
                            float* __restrict__ carry)
{
    int g = blockIdx.x * 256 + threadIdx.x;          // 0 .. B*16*768-1
    if (g >= BB * 16 * 768) return;
    int b  = g / (16 * 768);
    int nd = g % (16 * 768);

    float h0 = 0.0f;
    for (int c = 0; c < NC; ++c) {
        size_t idx = (size_t)(b * NC + c) * (16 * 768) + nd;
        float a = chunkA[idx];
        float hh = chunkH[idx];
        carry[idx] = h0;
        h0 = a * h0 + hh;
    }
}

__global__ __launch_bounds__(256)
void scan_phase3(const float* __restrict__ S,
                 const float* __restrict__ xz,
                 const float* __restrict__ A_log,
                 const float* __restrict__ Dp,
                 const float* __restrict__ carry,
                 short* __restrict__ yg)       // bf16 out: y_core * silu(z)
{
    int blk  = blockIdx.x;
    int b    = blk / (NC * 3);
    int rem  = blk % (NC * 3);
    int c    = rem / 3;
    int dblk = rem % 3;
    int d    = dblk * 256 + threadIdx.x;

    float Ac[16], h[16];
    size_t base = (size_t)(b * NC + c) * (16 * 768) + d;
    #pragma unroll
    for (int n = 0; n < 16; ++n) {
        Ac[n] = -__expf(A_log[(size_t)d * 16 + n]);
        h[n]  = carry[base + n * 768];
    }
    float Dv = Dp[d];

    int l0 = c * CL;
    for (int l = 0; l < CL; ++l) {
        int row = b * LL + l0 + l;
        const float* sr = S + (size_t)row * SLD;
        float delta = sr[d];
        float xp    = xz[(size_t)row * 1536 + d];
        float bx    = delta * xp;
        float4 B0 = *(const float4*)(sr + 768);
        float4 B1 = *(const float4*)(sr + 772);
        float4 B2 = *(const float4*)(sr + 776);
        float4 B3 = *(const float4*)(sr + 780);
        float4 C0 = *(const float4*)(sr + 784);
        float4 C1 = *(const float4*)(sr + 788);
        float4 C2 = *(const float4*)(sr + 792);
        float4 C3 = *(const float4*)(sr + 796);
        float Bv[16] = {B0.x,B0.y,B0.z,B0.w, B1.x,B1.y,B1.z,B1.w,
                        B2.x,B2.y,B2.z,B2.w, B3.x,B3.y,B3.z,B3.w};
        float Cv[16] = {C0.x,C0.y,C0.z,C0.w, C1.x,C1.y,C1.z,C1.w,
                        C2.x,C2.y,C2.z,C2.w, C3.x,C3.y,C3.z,C3.w};

        float acc = Dv * xp;
        #pragma unroll
        for (int n = 0; n < 16; ++n) {
            float dA = __expf(delta * Ac[n]);
            h[n] = dA * h[n] + bx * Bv[n];
            acc += Cv[n] * h[n];
        }
        float z = xz[(size_t)row * 1536 + 768 + d];
        yg[(size_t)row * 768 + d] = f2bf(acc * silu(z));
    }
}

// ---------------------------------------------------------------------------
// Workspace layout (float offsets), peak 74.1 MB — unchanged from Round 12:
//   xz : [0, 6291456)                live GEMM1..scan3
//   S  : [6291456, 9961472)          live GEMM2..scan3
//   AB = 9961472 (region of 6291456 floats = dead-Aug reuse):
//     xb  (bf16) @AB                 live convert..GEMM1
//     Aug (bf16) @AB                 live ln_aug..GEMM2
//     cA @AB+0        (1572864 f)    live scan1..scan2
//     cH @AB+1572864  (1572864 f)    live scan1..scan2
//     cc @AB+3145728  (1572864 f)    live scan2..scan3
//     yg (bf16) @AB+4718592          live scan3..GEMM3
//   WinT @16252928  WcatT @16842752  WoutT @18219008
// ---------------------------------------------------------------------------
extern "C" void kernel_launch(void* const* d_in, const int* in_sizes, int n_in,
                              void* d_out, int out_size, void* d_ws, size_t ws_size,
                              hipStream_t stream)
{
    const float* x        = (const float*)d_in[0];
    const float* prio     = (const float*)d_in[1];
    const float* W_in     = (const float*)d_in[2];
    const float* b_in     = (const float*)d_in[3];
    const float* ln_g     = (const float*)d_in[4];
    const float* ln_b     = (const float*)d_in[5];
    const float* kd_base  = (const float*)d_in[6];
    const float* kd_spl   = (const float*)d_in[7];
    const float* kb_base  = (const float*)d_in[8];
    const float* kb_spl   = (const float*)d_in[9];
    const float* kc_base  = (const float*)d_in[10];
    const float* kc_spl   = (const float*)d_in[11];
    const float* A_log    = (const float*)d_in[12];
    const float* D_param  = (const float*)d_in[13];
    const float* W_out    = (const float*)d_in[14];
    const float* b_out    = (const float*)d_in[15];
    float* out = (float*)d_out;

    float* ws    = (float*)d_ws;
    float* xz    = ws;
    float* S     = ws + 6291456;
    float* AB    = ws + 9961472;
    short* xb    = (short*)AB;                 // convert..GEMM1
    short* Aug   = (short*)AB;                 // ln_aug..GEMM2
    float* cA    = AB;                         // scan1..scan2
    float* cH    = AB + 1572864;
    float* cc    = AB + 3145728;               // scan2..scan3
    short* yg    = (short*)(AB + 4718592);     // scan3..GEMM3
    short* WinT  = (short*)(ws + 16252928);
    short* WcatT = (short*)(ws + 16842752);
    short* WoutT = (short*)(ws + 18219008);

    // --- weight prep + input convert ---
    convert_kernel<<<(MM * D_MODEL + 255) / 256, 256, 0, stream>>>(x, xb, MM * D_MODEL);
    wtrans_kernel<<<(768 * 1536 + 255) / 256, 256, 0, stream>>>(W_in, WinT, 768, 1536);
    repackT_kernel<<<(SLD * 3072 + 255) / 256, 256, 0, stream>>>(
        kd_base, kd_spl, kb_base, kb_spl, kc_base, kc_spl, WcatT);
    wtrans_kernel<<<(768 * 768 + 255) / 256, 256, 0, stream>>>(W_out, WoutT, 768, 768);

    // 1) xz = x @ W_in + b_in          [4096,1536], grid 24x64 = 1536 blocks
    gemm_bf16<<<dim3(1536 / 64, MM / 64), 256, 0, stream>>>(
        xb, WinT, b_in, nullptr, xz, MM, 1536, 768);

    // 2+3) LN + KAN augmentation -> Aug bf16 [4096,3072]
    ln_aug_kernel<<<MM, 256, 0, stream>>>(xz, ln_g, ln_b, Aug);

    // 4) S = Aug @ W_cat, delta fused   [4096,896], grid 14x64 = 896 blocks
    gemm_bf16<<<dim3(SLD / 64, MM / 64), 256, 0, stream>>>(
        Aug, WcatT, nullptr, prio, S, MM, SLD, 3072);

    // 5) chunked selective scan (gate fused into phase3 -> yg bf16)
    scan_phase1<<<BB * NC * 3, 256, 0, stream>>>(S, xz, A_log, cA, cH);
    scan_phase2<<<(BB * 16 * 768 + 255) / 256, 256, 0, stream>>>(cA, cH, cc);
    scan_phase3<<<BB * NC * 3, 256, 0, stream>>>(S, xz, A_log, D_param, cc, yg);

    // 6) out = yg @ W_out + b_out      [4096,768], grid 12x64 = 768 blocks
    gemm_bf16<<<dim3(768 / 64, MM / 64), 256, 0, stream>>>(
        yg, WoutT, b_out, nullptr, out, MM, 768, 768);
}